// Round 1
// 410.721 us; speedup vs baseline: 2.8763x; 2.8763x over previous
//
#include <hip/hip_runtime.h>
#include <hip/hip_bf16.h>
#include <math.h>

#define SEQ     512
#define BSZ     2
#define ROWS    (BSZ*SEQ)      // 1024
#define DMODEL  768
#define DINNER  1536
#define DSTATE  64
#define NHEADS  24
#define HEADDIM 64
#define CONVDIM 1664
#define DINPROJ 3224
#define DFF     3072
#define EPSF    1e-5f

typedef __attribute__((ext_vector_type(8))) short s16x8;   // 8 bf16 = 4 VGPRs
typedef __attribute__((ext_vector_type(4))) float f32x4;   // MFMA accumulator

__device__ __forceinline__ float b2f(const __hip_bfloat16 v){ return __bfloat162float(v); }
__device__ __forceinline__ __hip_bfloat16 f2b(float v){ return __float2bfloat16(v); }
__device__ __forceinline__ ushort f2bu(float v){
  union { __hip_bfloat16 b; ushort u; } c; c.b = __float2bfloat16(v); return c.u;
}

__device__ __forceinline__ float block_sum256(float v, float* sh){
  #pragma unroll
  for (int off = 32; off > 0; off >>= 1) v += __shfl_down(v, off, 64);
  int w = threadIdx.x >> 6;
  if ((threadIdx.x & 63) == 0) sh[w] = v;
  __syncthreads();
  float t = sh[0] + sh[1] + sh[2] + sh[3];
  __syncthreads();
  return t;
}

__global__ __launch_bounds__(256) void zerof_kernel(float* out, int n){
  int i = blockIdx.x*256 + threadIdx.x;
  if (i < n) out[i] = 0.f;
}

// ---- LayerNorm over 768: fp32 in, fp32 params, bf16 out (internal) ----
__global__ __launch_bounds__(256) void ln_kernel(const float* __restrict__ in,
    const float* __restrict__ w, const float* __restrict__ b,
    __hip_bfloat16* __restrict__ out)
{
  __shared__ float sh[4];
  const int row = blockIdx.x;
  const float* xr = in + (size_t)row * DMODEL;
  float v[3]; float s = 0.f;
  #pragma unroll
  for (int i = 0; i < 3; i++){ int c = threadIdx.x + i*256; v[i] = xr[c]; s += v[i]; }
  s = block_sum256(s, sh);
  float mu = s * (1.f/DMODEL);
  float s2 = 0.f;
  #pragma unroll
  for (int i = 0; i < 3; i++){ float d = v[i]-mu; s2 += d*d; }
  s2 = block_sum256(s2, sh);
  float rs = rsqrtf(s2*(1.f/DMODEL) + EPSF);
  #pragma unroll
  for (int i = 0; i < 3; i++){
    int c = threadIdx.x + i*256;
    out[(size_t)row*DMODEL + c] = f2b((v[i]-mu)*rs*w[c] + b[c]);
  }
}

// ---- MFMA GEMM: C(MxN) = A(MxK, bf16) @ B(NxK, fp32 weights)^T ----
// 64x64 tile, BK=64, 4 waves in 2x2 grid, each wave 32x32 via 2x2 16x16x32 frags.
// B converted fp32->bf16 in registers during staging. fp32 accumulation.
__device__ __forceinline__ s16x8 ld_frag(const ushort* p){
  union { ushort4 h[2]; s16x8 v; } u;
  u.h[0] = *(const ushort4*)(p);
  u.h[1] = *(const ushort4*)(p + 4);
  return u.v;
}

template<typename CTy>
__global__ __launch_bounds__(256) void gemm_mfma(const __hip_bfloat16* __restrict__ A,
    const float* __restrict__ B, CTy* __restrict__ C, int M, int N, int K)
{
  // +8 pad: row stride 144 B -> b64 frag reads are only 2-way bank-aliased (free)
  __shared__ __align__(16) ushort As[64][72];
  __shared__ __align__(16) ushort Bs[64][72];
  const int tid  = threadIdx.x;
  const int lane = tid & 63, wave = tid >> 6;
  const int wr = wave >> 1, wc = wave & 1;        // 2x2 wave grid
  const int n0 = blockIdx.x * 64, m0 = blockIdx.y * 64;
  const int sr = tid >> 2;                        // staging row 0..63
  const int sc = (tid & 3) * 16;                  // staging k-offset {0,16,32,48}
  const int l15 = lane & 15, lk = (lane >> 4) * 8;

  f32x4 acc[2][2] = {};

  const ushort* Au = (const ushort*)A;
  int nr = n0 + sr; if (nr > N-1) nr = N-1;       // clamp; garbage cols never stored

  for (int k0 = 0; k0 < K; k0 += 64){
    // global -> regs (issued before the sync so they overlap prior compute)
    const ushort* ag = Au + (size_t)(m0 + sr)*K + (k0 + sc);
    ushort4 a0 = *(const ushort4*)(ag);
    ushort4 a1 = *(const ushort4*)(ag + 4);
    ushort4 a2 = *(const ushort4*)(ag + 8);
    ushort4 a3 = *(const ushort4*)(ag + 12);
    const float* bg = B + (size_t)nr*K + (k0 + sc);
    float4 f0 = *(const float4*)(bg);
    float4 f1 = *(const float4*)(bg + 4);
    float4 f2 = *(const float4*)(bg + 8);
    float4 f3 = *(const float4*)(bg + 12);
    ushort4 b0 = make_ushort4(f2bu(f0.x), f2bu(f0.y), f2bu(f0.z), f2bu(f0.w));
    ushort4 b1 = make_ushort4(f2bu(f1.x), f2bu(f1.y), f2bu(f1.z), f2bu(f1.w));
    ushort4 b2 = make_ushort4(f2bu(f2.x), f2bu(f2.y), f2bu(f2.z), f2bu(f2.w));
    ushort4 b3 = make_ushort4(f2bu(f3.x), f2bu(f3.y), f2bu(f3.z), f2bu(f3.w));

    __syncthreads();   // previous iteration's frag reads must finish
    *(ushort4*)&As[sr][sc +  0] = a0;
    *(ushort4*)&As[sr][sc +  4] = a1;
    *(ushort4*)&As[sr][sc +  8] = a2;
    *(ushort4*)&As[sr][sc + 12] = a3;
    *(ushort4*)&Bs[sr][sc +  0] = b0;
    *(ushort4*)&Bs[sr][sc +  4] = b1;
    *(ushort4*)&Bs[sr][sc +  8] = b2;
    *(ushort4*)&Bs[sr][sc + 12] = b3;
    __syncthreads();

    #pragma unroll
    for (int kk = 0; kk < 64; kk += 32){
      s16x8 af0 = ld_frag(&As[wr*32      + l15][kk + lk]);
      s16x8 af1 = ld_frag(&As[wr*32 + 16 + l15][kk + lk]);
      s16x8 bf0 = ld_frag(&Bs[wc*32      + l15][kk + lk]);
      s16x8 bf1 = ld_frag(&Bs[wc*32 + 16 + l15][kk + lk]);
      acc[0][0] = __builtin_amdgcn_mfma_f32_16x16x32_bf16(af0, bf0, acc[0][0], 0, 0, 0);
      acc[0][1] = __builtin_amdgcn_mfma_f32_16x16x32_bf16(af0, bf1, acc[0][1], 0, 0, 0);
      acc[1][0] = __builtin_amdgcn_mfma_f32_16x16x32_bf16(af1, bf0, acc[1][0], 0, 0, 0);
      acc[1][1] = __builtin_amdgcn_mfma_f32_16x16x32_bf16(af1, bf1, acc[1][1], 0, 0, 0);
    }
  }

  // C/D layout (verified m89/m91): col = lane&15, row = (lane>>4)*4 + reg
  const int crow = (lane >> 4) * 4;
  #pragma unroll
  for (int i = 0; i < 2; i++){
    #pragma unroll
    for (int j = 0; j < 2; j++){
      int col = n0 + wc*32 + j*16 + l15;
      if (col < N){
        #pragma unroll
        for (int q = 0; q < 4; q++){
          int rowg = m0 + wr*32 + i*16 + crow + q;
          if constexpr (sizeof(CTy) == 4) C[(size_t)rowg*N + col] = acc[i][j][q];
          else                            C[(size_t)rowg*N + col] = (CTy)f2b(acc[i][j][q]);
        }
      }
    }
  }
}

// ---- causal depthwise conv(4) + bias + silu (both dirs) + dt/dA prep ----
// grid (SEQ, BSZ, 2). dir=1 in flipped (scan-time) coords; zx is bf16 internal.
__global__ __launch_bounds__(256) void convdt_kernel(const __hip_bfloat16* __restrict__ zx,
    const float* __restrict__ cw, const float* __restrict__ cb,
    const float* __restrict__ dt_bias, const float* __restrict__ A_log,
    __hip_bfloat16* __restrict__ xconv, float* __restrict__ dtb, float* __restrict__ dab)
{
  const int tt = blockIdx.x, b = blockIdx.y, dir = blockIdx.z;
  size_t rowoff[4]; bool ok[4];
  #pragma unroll
  for (int k = 0; k < 4; k++){
    int s = tt - 3 + k;
    ok[k] = (s >= 0);
    int ss = ok[k] ? s : 0;
    int phys = dir ? (SEQ-1-ss) : ss;
    rowoff[k] = ((size_t)(b*SEQ + phys))*DINPROJ + DINNER;
  }
  __hip_bfloat16* outr = xconv + ((size_t)((dir*BSZ + b)*SEQ + tt))*CONVDIM;
  for (int c = threadIdx.x; c < CONVDIM; c += 256){
    float acc = cb[c];
    #pragma unroll
    for (int k = 0; k < 4; k++){
      if (ok[k]) acc += cw[c*4 + k] * b2f(zx[rowoff[k] + c]);
    }
    outr[c] = f2b(acc / (1.f + expf(-acc)));   // silu
  }
  if (dir == 0 && threadIdx.x < NHEADS){
    int h = threadIdx.x;
    size_t r = (size_t)b*SEQ + tt;
    float raw = b2f(zx[r*DINPROJ + (DINNER + CONVDIM) + h]) + dt_bias[h];
    float sp  = fmaxf(raw, 0.f) + log1pf(expf(-fabsf(raw)));   // stable softplus
    dtb[r*NHEADS + h] = sp;
    dab[r*NHEADS + h] = expf(-sp * expf(A_log[h]));
  }
}

// ---- selective scan per (h, b, dir); 4 waves split 64 states; lane = p ----
#define CT 16
__global__ __launch_bounds__(256) void scan_kernel(const __hip_bfloat16* __restrict__ xconv,
    const __hip_bfloat16* __restrict__ zx, const float* __restrict__ dtb, const float* __restrict__ dab,
    const float* __restrict__ Dp, __hip_bfloat16* __restrict__ yg)
{
  const int h = blockIdx.x, b = blockIdx.y, dir = blockIdx.z;
  const int tid = threadIdx.x, lane = tid & 63, wave = tid >> 6, nb = wave * 16;
  __shared__ __align__(16) float Bc[CT][64], Cc[CT][64], Xc[CT][64];
  __shared__ __align__(16) float Yp[4][CT][64];
  __shared__ float dAc[CT], dtc[CT];
  float hreg[16];
  #pragma unroll
  for (int j = 0; j < 16; j++) hreg[j] = 0.f;
  const float Dh = Dp[h];
  const size_t dirbase = (size_t)(dir*BSZ + b) * SEQ;

  for (int c0 = 0; c0 < SEQ; c0 += CT){
    for (int i = tid; i < CT*64; i += 256){
      int ttl = i >> 6, cc = i & 63;
      const __hip_bfloat16* rowp = xconv + (dirbase + c0 + ttl)*CONVDIM;
      Bc[ttl][cc] = b2f(rowp[DINNER + cc]);
      Cc[ttl][cc] = b2f(rowp[DINNER + DSTATE + cc]);
      Xc[ttl][cc] = b2f(rowp[h*HEADDIM + cc]);
    }
    if (tid < CT){
      int phys = dir ? (SEQ-1 - (c0 + tid)) : (c0 + tid);
      size_t r = (size_t)b*SEQ + phys;
      dAc[tid] = dab[r*NHEADS + h];
      dtc[tid] = dtb[r*NHEADS + h];
    }
    __syncthreads();

    #pragma unroll 4
    for (int tt = 0; tt < CT; tt++){
      float dA = dAc[tt], dtv = dtc[tt];
      float dtx = dtv * Xc[tt][lane];
      float y0 = 0.f, y1 = 0.f, y2 = 0.f, y3 = 0.f;
      #pragma unroll
      for (int q = 0; q < 4; q++){
        int j = q*4, n = nb + j;
        float B0 = Bc[tt][n+0], B1 = Bc[tt][n+1], B2 = Bc[tt][n+2], B3 = Bc[tt][n+3];
        float C0 = Cc[tt][n+0], C1 = Cc[tt][n+1], C2 = Cc[tt][n+2], C3 = Cc[tt][n+3];
        hreg[j+0] = fmaf(dA, hreg[j+0], dtx*B0); y0 = fmaf(hreg[j+0], C0, y0);
        hreg[j+1] = fmaf(dA, hreg[j+1], dtx*B1); y1 = fmaf(hreg[j+1], C1, y1);
        hreg[j+2] = fmaf(dA, hreg[j+2], dtx*B2); y2 = fmaf(hreg[j+2], C2, y2);
        hreg[j+3] = fmaf(dA, hreg[j+3], dtx*B3); y3 = fmaf(hreg[j+3], C3, y3);
      }
      Yp[wave][tt][lane] = (y0+y1) + (y2+y3);
    }
    __syncthreads();

    for (int i = tid; i < CT*64; i += 256){
      int ttl = i >> 6, p = i & 63;
      float y = Yp[0][ttl][p] + Yp[1][ttl][p] + Yp[2][ttl][p] + Yp[3][ttl][p]
              + Dh * Xc[ttl][p];
      int phys = dir ? (SEQ-1 - (c0 + ttl)) : (c0 + ttl);
      size_t r = (size_t)b*SEQ + phys;
      float zval = b2f(zx[r*DINPROJ + h*HEADDIM + p]);
      float sil  = zval / (1.f + expf(-zval));
      yg[((size_t)dir*ROWS + r)*DINNER + h*HEADDIM + p] = f2b(y * sil);
    }
    __syncthreads();
  }
}

// ---- per-row gated RMSNorm both dirs + combine (fp32 norm_w) -> u bf16 ----
__global__ __launch_bounds__(256) void rmscomb_kernel(const __hip_bfloat16* __restrict__ yg,
    const float* __restrict__ nw, __hip_bfloat16* __restrict__ u)
{
  __shared__ float sh[4];
  const int row = blockIdx.x;
  const __hip_bfloat16* yf = yg + (size_t)row*DINNER;
  const __hip_bfloat16* yb = yg + (size_t)(ROWS + row)*DINNER;
  float vf[6], vb[6]; float sf = 0.f, sb = 0.f;
  #pragma unroll
  for (int i = 0; i < 6; i++){
    int c = threadIdx.x + i*256;
    vf[i] = b2f(yf[c]); sf += vf[i]*vf[i];
    vb[i] = b2f(yb[c]); sb += vb[i]*vb[i];
  }
  sf = block_sum256(sf, sh);
  sb = block_sum256(sb, sh);
  float rf = rsqrtf(sf*(1.f/DINNER) + EPSF);
  float rb = rsqrtf(sb*(1.f/DINNER) + EPSF);
  #pragma unroll
  for (int i = 0; i < 6; i++){
    int c = threadIdx.x + i*256;
    u[(size_t)row*DINNER + c] = f2b((vf[i]*rf + vb[i]*rb) * nw[c]);
  }
}

// ---- ln2 on fp32 mo -> bf16 mb ----
__global__ __launch_bounds__(256) void ln2_kernel(const float* __restrict__ in,
    const float* __restrict__ w, const float* __restrict__ b,
    __hip_bfloat16* __restrict__ out)
{
  __shared__ float sh[4];
  const int row = blockIdx.x;
  const float* xr = in + (size_t)row * DMODEL;
  float v[3]; float s = 0.f;
  #pragma unroll
  for (int i = 0; i < 3; i++){ int c = threadIdx.x + i*256; v[i] = xr[c]; s += v[i]; }
  s = block_sum256(s, sh);
  float mu = s * (1.f/DMODEL);
  float s2 = 0.f;
  #pragma unroll
  for (int i = 0; i < 3; i++){ float d = v[i]-mu; s2 += d*d; }
  s2 = block_sum256(s2, sh);
  float rs = rsqrtf(s2*(1.f/DMODEL) + EPSF);
  #pragma unroll
  for (int i = 0; i < 3; i++){
    int c = threadIdx.x + i*256;
    out[(size_t)row*DMODEL + c] = f2b((v[i]-mu)*rs*w[c] + b[c]);
  }
}

// ---- exact GELU with fp32 bias: bf16 g -> bf16 gb ----
__global__ __launch_bounds__(256) void gelu_kernel(const __hip_bfloat16* __restrict__ g,
    const float* __restrict__ b1, __hip_bfloat16* __restrict__ out)
{
  size_t idx = (size_t)blockIdx.x*256 + threadIdx.x;
  int c = (int)(idx % DFF);
  float v = b2f(g[idx]) + b1[c];
  out[idx] = f2b(0.5f * v * (1.f + erff(v * 0.70710678118654752f)));
}

// ---- final: fp32 fo + fp32 bias + fp32 x -> fp32 out ----
__global__ __launch_bounds__(256) void final_kernel(const float* __restrict__ f,
    const float* __restrict__ bias, const float* __restrict__ x,
    float* __restrict__ out)
{
  size_t idx = (size_t)blockIdx.x*256 + threadIdx.x;
  int c = (int)(idx % DMODEL);
  out[idx] = f[idx] + bias[c] + x[idx];
}

extern "C" void kernel_launch(void* const* d_in, const int* in_sizes, int n_in,
                              void* d_out, int out_size, void* d_ws, size_t ws_size,
                              hipStream_t stream)
{
  float* out = (float*)d_out;

  const size_t NEED = 19906560;   // proven to fit (r3 guard passed)
  if (ws_size < NEED || n_in < 17){
    zerof_kernel<<<(out_size + 255)/256, 256, 0, stream>>>(out, out_size);
    return;
  }

  const float* x       = (const float*)d_in[0];
  const float* in_proj_w = (const float*)d_in[1];
  const float* conv_w  = (const float*)d_in[2];
  const float* conv_b  = (const float*)d_in[3];
  const float* dt_bias = (const float*)d_in[4];
  const float* A_log   = (const float*)d_in[5];
  const float* D_param = (const float*)d_in[6];
  const float* norm_w  = (const float*)d_in[7];
  const float* out_proj_w = (const float*)d_in[8];
  const float* ln1_w   = (const float*)d_in[9];
  const float* ln1_b   = (const float*)d_in[10];
  const float* ln2_w   = (const float*)d_in[11];
  const float* ln2_b   = (const float*)d_in[12];
  const float* ff_w1   = (const float*)d_in[13];
  const float* ff_b1   = (const float*)d_in[14];
  const float* ff_w2   = (const float*)d_in[15];
  const float* ff_b2   = (const float*)d_in[16];

  // bf16-internal workspace, same proven 19.9 MB plan as r3:
  char* ws = (char*)d_ws;
  __hip_bfloat16* zx  = (__hip_bfloat16*)(ws + 0);         // 6,602,752
  __hip_bfloat16* xn  = (__hip_bfloat16*)(ws + 6602752);   // 1,572,864 (dead after s2)
  float*          dtb = (float*)(ws + 6602752);            //    98,304 (over xn)
  float*          dab = (float*)(ws + 6701056);            //    98,304
  __hip_bfloat16* xcv = (__hip_bfloat16*)(ws + 6799360);   // 6,815,744 -> 13,615,104
  __hip_bfloat16* yg  = (__hip_bfloat16*)(ws + 13615104);  // 6,291,456 -> 19,906,560
  __hip_bfloat16* u   = (__hip_bfloat16*)(ws + 0);         // over zx (dead after scan)
  float*          mo  = (float*)(ws + 3145728);            // over zx
  __hip_bfloat16* mb  = (__hip_bfloat16*)(ws + 0);         // over u (dead)
  __hip_bfloat16* g   = (__hip_bfloat16*)(ws + 6799360);   // over xcv (dead)
  __hip_bfloat16* gb  = (__hip_bfloat16*)(ws + 13615104);  // over yg (dead)
  float*          fo  = (float*)(ws + 0);                  // over mb (dead)

  // 1) ln1(x) -> xn
  ln_kernel<<<ROWS, 256, 0, stream>>>(x, ln1_w, ln1_b, xn);
  // 2) in_proj (shared fwd/bwd) -> zx bf16  [MFMA]
  gemm_mfma<<<dim3((DINPROJ+63)/64, ROWS/64), 256, 0, stream>>>(xn, in_proj_w, zx, ROWS, DINPROJ, DMODEL);
  // 3) conv + silu + dt/dA
  convdt_kernel<<<dim3(SEQ, BSZ, 2), 256, 0, stream>>>(zx, conv_w, conv_b, dt_bias, A_log, xcv, dtb, dab);
  // 4) scan + D*x + silu(z) gate -> yg
  scan_kernel<<<dim3(NHEADS, BSZ, 2), 256, 0, stream>>>(xcv, zx, dtb, dab, D_param, yg);
  // 5) per-dir RMS + combine -> u
  rmscomb_kernel<<<ROWS, 256, 0, stream>>>(yg, norm_w, u);
  // 6) out_proj -> mo fp32  [MFMA]
  gemm_mfma<<<dim3(DMODEL/64, ROWS/64), 256, 0, stream>>>(u, out_proj_w, mo, ROWS, DMODEL, DINNER);
  // 7) ln2 -> mb
  ln2_kernel<<<ROWS, 256, 0, stream>>>(mo, ln2_w, ln2_b, mb);
  // 8) ff1 -> g  [MFMA]
  gemm_mfma<<<dim3(DFF/64, ROWS/64), 256, 0, stream>>>(mb, ff_w1, g, ROWS, DFF, DMODEL);
  // 9) gelu -> gb
  gelu_kernel<<<(ROWS*DFF)/256, 256, 0, stream>>>(g, ff_b1, gb);
  // 10) ff2 -> fo fp32  [MFMA]
  gemm_mfma<<<dim3(DMODEL/64, ROWS/64), 256, 0, stream>>>(gb, ff_w2, fo, ROWS, DMODEL, DFF);
  // 11) + b2 + residual -> out fp32
  final_kernel<<<(ROWS*DMODEL)/256, 256, 0, stream>>>(fo, ff_b2, x, out);
}

// Round 2
// 311.663 us; speedup vs baseline: 3.7905x; 1.3178x over previous
//
#include <hip/hip_runtime.h>
#include <hip/hip_bf16.h>
#include <math.h>

#define SEQ     512
#define BSZ     2
#define ROWS    (BSZ*SEQ)      // 1024
#define DMODEL  768
#define DINNER  1536
#define DSTATE  64
#define NHEADS  24
#define HEADDIM 64
#define CONVDIM 1664
#define DINPROJ 3224
#define DFF     3072
#define EPSF    1e-5f

typedef __attribute__((ext_vector_type(8))) short s16x8;   // 8 bf16 = 4 VGPRs
typedef __attribute__((ext_vector_type(4))) float f32x4;   // MFMA accumulator

__device__ __forceinline__ float b2f(const __hip_bfloat16 v){ return __bfloat162float(v); }
__device__ __forceinline__ __hip_bfloat16 f2b(float v){ return __float2bfloat16(v); }
__device__ __forceinline__ ushort f2bu(float v){
  union { __hip_bfloat16 b; ushort u; } c; c.b = __float2bfloat16(v); return c.u;
}
__device__ __forceinline__ float u2f(ushort u){ return __uint_as_float(((uint)u) << 16); }

__device__ __forceinline__ float block_sum256(float v, float* sh){
  #pragma unroll
  for (int off = 32; off > 0; off >>= 1) v += __shfl_down(v, off, 64);
  int w = threadIdx.x >> 6;
  if ((threadIdx.x & 63) == 0) sh[w] = v;
  __syncthreads();
  float t = sh[0] + sh[1] + sh[2] + sh[3];
  __syncthreads();
  return t;
}

__global__ __launch_bounds__(256) void zerof_kernel(float* out, int n){
  int i = blockIdx.x*256 + threadIdx.x;
  if (i < n) out[i] = 0.f;
}

// ---- LayerNorm over 768: fp32 in, fp32 params, bf16 out (internal) ----
__global__ __launch_bounds__(256) void ln_kernel(const float* __restrict__ in,
    const float* __restrict__ w, const float* __restrict__ b,
    __hip_bfloat16* __restrict__ out)
{
  __shared__ float sh[4];
  const int row = blockIdx.x;
  const float* xr = in + (size_t)row * DMODEL;
  float v[3]; float s = 0.f;
  #pragma unroll
  for (int i = 0; i < 3; i++){ int c = threadIdx.x + i*256; v[i] = xr[c]; s += v[i]; }
  s = block_sum256(s, sh);
  float mu = s * (1.f/DMODEL);
  float s2 = 0.f;
  #pragma unroll
  for (int i = 0; i < 3; i++){ float d = v[i]-mu; s2 += d*d; }
  s2 = block_sum256(s2, sh);
  float rs = rsqrtf(s2*(1.f/DMODEL) + EPSF);
  #pragma unroll
  for (int i = 0; i < 3; i++){
    int c = threadIdx.x + i*256;
    out[(size_t)row*DMODEL + c] = f2b((v[i]-mu)*rs*w[c] + b[c]);
  }
}

// ---- MFMA GEMM: C(MxN) = A(MxK, bf16) @ B(NxK, fp32 weights)^T ----
__device__ __forceinline__ s16x8 ld_frag(const ushort* p){
  union { ushort4 h[2]; s16x8 v; } u;
  u.h[0] = *(const ushort4*)(p);
  u.h[1] = *(const ushort4*)(p + 4);
  return u.v;
}

template<typename CTy>
__global__ __launch_bounds__(256) void gemm_mfma(const __hip_bfloat16* __restrict__ A,
    const float* __restrict__ B, CTy* __restrict__ C, int M, int N, int K)
{
  __shared__ __align__(16) ushort As[64][72];
  __shared__ __align__(16) ushort Bs[64][72];
  const int tid  = threadIdx.x;
  const int lane = tid & 63, wave = tid >> 6;
  const int wr = wave >> 1, wc = wave & 1;        // 2x2 wave grid
  const int n0 = blockIdx.x * 64, m0 = blockIdx.y * 64;
  const int sr = tid >> 2;                        // staging row 0..63
  const int sc = (tid & 3) * 16;                  // staging k-offset {0,16,32,48}
  const int l15 = lane & 15, lk = (lane >> 4) * 8;

  f32x4 acc[2][2] = {};

  const ushort* Au = (const ushort*)A;
  int nr = n0 + sr; if (nr > N-1) nr = N-1;       // clamp; garbage cols never stored

  for (int k0 = 0; k0 < K; k0 += 64){
    const ushort* ag = Au + (size_t)(m0 + sr)*K + (k0 + sc);
    ushort4 a0 = *(const ushort4*)(ag);
    ushort4 a1 = *(const ushort4*)(ag + 4);
    ushort4 a2 = *(const ushort4*)(ag + 8);
    ushort4 a3 = *(const ushort4*)(ag + 12);
    const float* bg = B + (size_t)nr*K + (k0 + sc);
    float4 f0 = *(const float4*)(bg);
    float4 f1 = *(const float4*)(bg + 4);
    float4 f2 = *(const float4*)(bg + 8);
    float4 f3 = *(const float4*)(bg + 12);
    ushort4 b0 = make_ushort4(f2bu(f0.x), f2bu(f0.y), f2bu(f0.z), f2bu(f0.w));
    ushort4 b1 = make_ushort4(f2bu(f1.x), f2bu(f1.y), f2bu(f1.z), f2bu(f1.w));
    ushort4 b2 = make_ushort4(f2bu(f2.x), f2bu(f2.y), f2bu(f2.z), f2bu(f2.w));
    ushort4 b3 = make_ushort4(f2bu(f3.x), f2bu(f3.y), f2bu(f3.z), f2bu(f3.w));

    __syncthreads();
    *(ushort4*)&As[sr][sc +  0] = a0;
    *(ushort4*)&As[sr][sc +  4] = a1;
    *(ushort4*)&As[sr][sc +  8] = a2;
    *(ushort4*)&As[sr][sc + 12] = a3;
    *(ushort4*)&Bs[sr][sc +  0] = b0;
    *(ushort4*)&Bs[sr][sc +  4] = b1;
    *(ushort4*)&Bs[sr][sc +  8] = b2;
    *(ushort4*)&Bs[sr][sc + 12] = b3;
    __syncthreads();

    #pragma unroll
    for (int kk = 0; kk < 64; kk += 32){
      s16x8 af0 = ld_frag(&As[wr*32      + l15][kk + lk]);
      s16x8 af1 = ld_frag(&As[wr*32 + 16 + l15][kk + lk]);
      s16x8 bf0 = ld_frag(&Bs[wc*32      + l15][kk + lk]);
      s16x8 bf1 = ld_frag(&Bs[wc*32 + 16 + l15][kk + lk]);
      acc[0][0] = __builtin_amdgcn_mfma_f32_16x16x32_bf16(af0, bf0, acc[0][0], 0, 0, 0);
      acc[0][1] = __builtin_amdgcn_mfma_f32_16x16x32_bf16(af0, bf1, acc[0][1], 0, 0, 0);
      acc[1][0] = __builtin_amdgcn_mfma_f32_16x16x32_bf16(af1, bf0, acc[1][0], 0, 0, 0);
      acc[1][1] = __builtin_amdgcn_mfma_f32_16x16x32_bf16(af1, bf1, acc[1][1], 0, 0, 0);
    }
  }

  // C/D layout (verified m89/m91): col = lane&15, row = (lane>>4)*4 + reg
  const int crow = (lane >> 4) * 4;
  #pragma unroll
  for (int i = 0; i < 2; i++){
    #pragma unroll
    for (int j = 0; j < 2; j++){
      int col = n0 + wc*32 + j*16 + l15;
      if (col < N){
        #pragma unroll
        for (int q = 0; q < 4; q++){
          int rowg = m0 + wr*32 + i*16 + crow + q;
          if constexpr (sizeof(CTy) == 4) C[(size_t)rowg*N + col] = acc[i][j][q];
          else                            C[(size_t)rowg*N + col] = (CTy)f2b(acc[i][j][q]);
        }
      }
    }
  }
}

// ---- causal depthwise conv(4) + bias + silu (both dirs) + dt/dA prep ----
__global__ __launch_bounds__(256) void convdt_kernel(const __hip_bfloat16* __restrict__ zx,
    const float* __restrict__ cw, const float* __restrict__ cb,
    const float* __restrict__ dt_bias, const float* __restrict__ A_log,
    __hip_bfloat16* __restrict__ xconv, float* __restrict__ dtb, float* __restrict__ dab)
{
  const int tt = blockIdx.x, b = blockIdx.y, dir = blockIdx.z;
  size_t rowoff[4]; bool ok[4];
  #pragma unroll
  for (int k = 0; k < 4; k++){
    int s = tt - 3 + k;
    ok[k] = (s >= 0);
    int ss = ok[k] ? s : 0;
    int phys = dir ? (SEQ-1-ss) : ss;
    rowoff[k] = ((size_t)(b*SEQ + phys))*DINPROJ + DINNER;
  }
  __hip_bfloat16* outr = xconv + ((size_t)((dir*BSZ + b)*SEQ + tt))*CONVDIM;
  for (int c = threadIdx.x; c < CONVDIM; c += 256){
    float acc = cb[c];
    #pragma unroll
    for (int k = 0; k < 4; k++){
      if (ok[k]) acc += cw[c*4 + k] * b2f(zx[rowoff[k] + c]);
    }
    outr[c] = f2b(acc / (1.f + expf(-acc)));   // silu
  }
  if (dir == 0 && threadIdx.x < NHEADS){
    int h = threadIdx.x;
    size_t r = (size_t)b*SEQ + tt;
    float raw = b2f(zx[r*DINPROJ + (DINNER + CONVDIM) + h]) + dt_bias[h];
    float sp  = fmaxf(raw, 0.f) + log1pf(expf(-fabsf(raw)));   // stable softplus
    dtb[r*NHEADS + h] = sp;
    dab[r*NHEADS + h] = expf(-sp * expf(A_log[h]));
  }
}

// ======================= chunked selective scan =======================
// h_t = dA_t * h_{t-1} + (dt_t x_t) B_t  (linear in h) -> split SEQ into NC
// chunks: pass1 computes local end-states (h=0 init); fixup recombines into
// per-chunk initial states; pass2 runs the full scan per chunk with h_init.
// state layout: stateBuf[((c*4 + z)*NHEADS + h)*4096 + p*64 + n], z = dir*2+b
#define CT 16

// pass1: local chunk scan, state update only. grid (NC-1, NHEADS, 4)
__global__ __launch_bounds__(256) void scan_pass1(const __hip_bfloat16* __restrict__ xconv,
    const float* __restrict__ dtb, const float* __restrict__ dab,
    float* __restrict__ stateBuf, int CL)
{
  const int c = blockIdx.x, h = blockIdx.y, z = blockIdx.z;
  const int b = z & 1, dir = z >> 1;
  const int tid = threadIdx.x, lane = tid & 63, wave = tid >> 6, nb = wave * 16;
  __shared__ __align__(16) float Bc[CT][64], Xc[CT][64];
  __shared__ float dAc[CT], dtc[CT];
  float hreg[16];
  #pragma unroll
  for (int j = 0; j < 16; j++) hreg[j] = 0.f;
  const size_t dirbase = (size_t)z * SEQ;
  const int cstart = c * CL;

  const int ttl = tid >> 4, c4 = (tid & 15) << 2;   // staging: 16 thr/row x 4 elems

  for (int c0 = cstart; c0 < cstart + CL; c0 += CT){
    {
      const ushort* rowp = (const ushort*)xconv + (dirbase + c0 + ttl)*(size_t)CONVDIM;
      ushort4 bv = *(const ushort4*)(rowp + DINNER + c4);
      ushort4 xv = *(const ushort4*)(rowp + h*HEADDIM + c4);
      Bc[ttl][c4+0] = u2f(bv.x); Bc[ttl][c4+1] = u2f(bv.y);
      Bc[ttl][c4+2] = u2f(bv.z); Bc[ttl][c4+3] = u2f(bv.w);
      Xc[ttl][c4+0] = u2f(xv.x); Xc[ttl][c4+1] = u2f(xv.y);
      Xc[ttl][c4+2] = u2f(xv.z); Xc[ttl][c4+3] = u2f(xv.w);
    }
    if (tid < CT){
      int phys = dir ? (SEQ-1 - (c0 + tid)) : (c0 + tid);
      size_t r = (size_t)b*SEQ + phys;
      dAc[tid] = dab[r*NHEADS + h];
      dtc[tid] = dtb[r*NHEADS + h];
    }
    __syncthreads();

    #pragma unroll 4
    for (int tt = 0; tt < CT; tt++){
      float dA = dAc[tt];
      float dtx = dtc[tt] * Xc[tt][lane];
      const float4* Bq = (const float4*)&Bc[tt][nb];
      float4 B0 = Bq[0], B1 = Bq[1], B2 = Bq[2], B3 = Bq[3];
      hreg[ 0]=fmaf(dA,hreg[ 0],dtx*B0.x); hreg[ 1]=fmaf(dA,hreg[ 1],dtx*B0.y);
      hreg[ 2]=fmaf(dA,hreg[ 2],dtx*B0.z); hreg[ 3]=fmaf(dA,hreg[ 3],dtx*B0.w);
      hreg[ 4]=fmaf(dA,hreg[ 4],dtx*B1.x); hreg[ 5]=fmaf(dA,hreg[ 5],dtx*B1.y);
      hreg[ 6]=fmaf(dA,hreg[ 6],dtx*B1.z); hreg[ 7]=fmaf(dA,hreg[ 7],dtx*B1.w);
      hreg[ 8]=fmaf(dA,hreg[ 8],dtx*B2.x); hreg[ 9]=fmaf(dA,hreg[ 9],dtx*B2.y);
      hreg[10]=fmaf(dA,hreg[10],dtx*B2.z); hreg[11]=fmaf(dA,hreg[11],dtx*B2.w);
      hreg[12]=fmaf(dA,hreg[12],dtx*B3.x); hreg[13]=fmaf(dA,hreg[13],dtx*B3.y);
      hreg[14]=fmaf(dA,hreg[14],dtx*B3.z); hreg[15]=fmaf(dA,hreg[15],dtx*B3.w);
    }
    __syncthreads();
  }

  float* sp = stateBuf + (((size_t)c*4 + z)*NHEADS + h)*4096 + (size_t)lane*64 + nb;
  *(float4*)(sp +  0) = make_float4(hreg[ 0],hreg[ 1],hreg[ 2],hreg[ 3]);
  *(float4*)(sp +  4) = make_float4(hreg[ 4],hreg[ 5],hreg[ 6],hreg[ 7]);
  *(float4*)(sp +  8) = make_float4(hreg[ 8],hreg[ 9],hreg[10],hreg[11]);
  *(float4*)(sp + 12) = make_float4(hreg[12],hreg[13],hreg[14],hreg[15]);
}

// fixup: h_init[c] = P_{c-1} h_init[c-1] + L_{c-1}; overwrites state[c] (c>=1).
// state[0] keeps L_0 but pass2 uses zeros for c==0. grid (NHEADS, 4)
__global__ __launch_bounds__(256) void scan_fixup(const float* __restrict__ dab,
    float* __restrict__ stateBuf, int NC, int CL)
{
  const int h = blockIdx.x, z = blockIdx.y;
  const int b = z & 1, dir = z >> 1;
  const int tid = threadIdx.x;
  __shared__ float sdA[SEQ];
  __shared__ float P[8];
  for (int i = tid; i < SEQ; i += 256){
    int phys = dir ? (SEQ-1-i) : i;
    sdA[i] = dab[((size_t)b*SEQ + phys)*NHEADS + h];
  }
  __syncthreads();
  if (tid < NC){
    float p = 1.f;
    for (int i = 0; i < CL; i++) p *= sdA[tid*CL + i];
    P[tid] = p;
  }
  __syncthreads();

  float hrun[16], Lcur[16];
  #pragma unroll
  for (int j = 0; j < 16; j++) hrun[j] = 0.f;
  {
    const float* s0 = stateBuf + ((size_t)z*NHEADS + h)*4096 + (size_t)tid*16;
    #pragma unroll
    for (int j = 0; j < 16; j++) Lcur[j] = s0[j];
  }
  for (int c = 1; c < NC; c++){
    float Pp = P[c-1];
    float hnew[16];
    #pragma unroll
    for (int j = 0; j < 16; j++) hnew[j] = fmaf(Pp, hrun[j], Lcur[j]);
    float* sc = stateBuf + (((size_t)c*4 + z)*NHEADS + h)*4096 + (size_t)tid*16;
    if (c < NC-1){
      #pragma unroll
      for (int j = 0; j < 16; j++) Lcur[j] = sc[j];   // read L_c before overwrite
    }
    #pragma unroll
    for (int j = 0; j < 16; j++) sc[j] = hnew[j];
    #pragma unroll
    for (int j = 0; j < 16; j++) hrun[j] = hnew[j];
  }
}

// pass2: full scan per chunk from h_init; y + D*x + silu(z) gate -> yg.
// grid (NC, NHEADS, 4)
__global__ __launch_bounds__(256) void scan_pass2(const __hip_bfloat16* __restrict__ xconv,
    const __hip_bfloat16* __restrict__ zx, const float* __restrict__ dtb,
    const float* __restrict__ dab, const float* __restrict__ Dp,
    const float* __restrict__ stateBuf, __hip_bfloat16* __restrict__ yg, int CL)
{
  const int c = blockIdx.x, h = blockIdx.y, z = blockIdx.z;
  const int b = z & 1, dir = z >> 1;
  const int tid = threadIdx.x, lane = tid & 63, wave = tid >> 6, nb = wave * 16;
  __shared__ __align__(16) float Bc[CT][64], Cc[CT][64], Xc[CT][64];
  __shared__ __align__(16) float Yp[4][CT][64];
  __shared__ float dAc[CT], dtc[CT];
  float hreg[16];
  if (c == 0){
    #pragma unroll
    for (int j = 0; j < 16; j++) hreg[j] = 0.f;
  } else {
    const float* sp = stateBuf + (((size_t)c*4 + z)*NHEADS + h)*4096 + (size_t)lane*64 + nb;
    float4 s0 = *(const float4*)(sp+0), s1 = *(const float4*)(sp+4);
    float4 s2 = *(const float4*)(sp+8), s3 = *(const float4*)(sp+12);
    hreg[ 0]=s0.x; hreg[ 1]=s0.y; hreg[ 2]=s0.z; hreg[ 3]=s0.w;
    hreg[ 4]=s1.x; hreg[ 5]=s1.y; hreg[ 6]=s1.z; hreg[ 7]=s1.w;
    hreg[ 8]=s2.x; hreg[ 9]=s2.y; hreg[10]=s2.z; hreg[11]=s2.w;
    hreg[12]=s3.x; hreg[13]=s3.y; hreg[14]=s3.z; hreg[15]=s3.w;
  }
  const float Dh = Dp[h];
  const size_t dirbase = (size_t)z * SEQ;
  const int cstart = c * CL;
  const int ttl = tid >> 4, c4 = (tid & 15) << 2;

  for (int c0 = cstart; c0 < cstart + CL; c0 += CT){
    {
      const ushort* rowp = (const ushort*)xconv + (dirbase + c0 + ttl)*(size_t)CONVDIM;
      ushort4 bv = *(const ushort4*)(rowp + DINNER + c4);
      ushort4 cv = *(const ushort4*)(rowp + DINNER + DSTATE + c4);
      ushort4 xv = *(const ushort4*)(rowp + h*HEADDIM + c4);
      Bc[ttl][c4+0] = u2f(bv.x); Bc[ttl][c4+1] = u2f(bv.y);
      Bc[ttl][c4+2] = u2f(bv.z); Bc[ttl][c4+3] = u2f(bv.w);
      Cc[ttl][c4+0] = u2f(cv.x); Cc[ttl][c4+1] = u2f(cv.y);
      Cc[ttl][c4+2] = u2f(cv.z); Cc[ttl][c4+3] = u2f(cv.w);
      Xc[ttl][c4+0] = u2f(xv.x); Xc[ttl][c4+1] = u2f(xv.y);
      Xc[ttl][c4+2] = u2f(xv.z); Xc[ttl][c4+3] = u2f(xv.w);
    }
    if (tid < CT){
      int phys = dir ? (SEQ-1 - (c0 + tid)) : (c0 + tid);
      size_t r = (size_t)b*SEQ + phys;
      dAc[tid] = dab[r*NHEADS + h];
      dtc[tid] = dtb[r*NHEADS + h];
    }
    __syncthreads();

    #pragma unroll 4
    for (int tt = 0; tt < CT; tt++){
      float dA = dAc[tt];
      float dtx = dtc[tt] * Xc[tt][lane];
      const float4* Bq = (const float4*)&Bc[tt][nb];
      const float4* Cq = (const float4*)&Cc[tt][nb];
      float4 B0 = Bq[0], B1 = Bq[1], B2 = Bq[2], B3 = Bq[3];
      float4 C0 = Cq[0], C1 = Cq[1], C2 = Cq[2], C3 = Cq[3];
      float y0 = 0.f, y1 = 0.f, y2 = 0.f, y3 = 0.f;
      hreg[ 0]=fmaf(dA,hreg[ 0],dtx*B0.x); y0=fmaf(hreg[ 0],C0.x,y0);
      hreg[ 1]=fmaf(dA,hreg[ 1],dtx*B0.y); y1=fmaf(hreg[ 1],C0.y,y1);
      hreg[ 2]=fmaf(dA,hreg[ 2],dtx*B0.z); y2=fmaf(hreg[ 2],C0.z,y2);
      hreg[ 3]=fmaf(dA,hreg[ 3],dtx*B0.w); y3=fmaf(hreg[ 3],C0.w,y3);
      hreg[ 4]=fmaf(dA,hreg[ 4],dtx*B1.x); y0=fmaf(hreg[ 4],C1.x,y0);
      hreg[ 5]=fmaf(dA,hreg[ 5],dtx*B1.y); y1=fmaf(hreg[ 5],C1.y,y1);
      hreg[ 6]=fmaf(dA,hreg[ 6],dtx*B1.z); y2=fmaf(hreg[ 6],C1.z,y2);
      hreg[ 7]=fmaf(dA,hreg[ 7],dtx*B1.w); y3=fmaf(hreg[ 7],C1.w,y3);
      hreg[ 8]=fmaf(dA,hreg[ 8],dtx*B2.x); y0=fmaf(hreg[ 8],C2.x,y0);
      hreg[ 9]=fmaf(dA,hreg[ 9],dtx*B2.y); y1=fmaf(hreg[ 9],C2.y,y1);
      hreg[10]=fmaf(dA,hreg[10],dtx*B2.z); y2=fmaf(hreg[10],C2.z,y2);
      hreg[11]=fmaf(dA,hreg[11],dtx*B2.w); y3=fmaf(hreg[11],C2.w,y3);
      hreg[12]=fmaf(dA,hreg[12],dtx*B3.x); y0=fmaf(hreg[12],C3.x,y0);
      hreg[13]=fmaf(dA,hreg[13],dtx*B3.y); y1=fmaf(hreg[13],C3.y,y1);
      hreg[14]=fmaf(dA,hreg[14],dtx*B3.z); y2=fmaf(hreg[14],C3.z,y2);
      hreg[15]=fmaf(dA,hreg[15],dtx*B3.w); y3=fmaf(hreg[15],C3.w,y3);
      Yp[wave][tt][lane] = (y0+y1) + (y2+y3);
    }
    __syncthreads();

    for (int i = tid; i < CT*64; i += 256){
      int tl = i >> 6, p = i & 63;
      float y = Yp[0][tl][p] + Yp[1][tl][p] + Yp[2][tl][p] + Yp[3][tl][p]
              + Dh * Xc[tl][p];
      int phys = dir ? (SEQ-1 - (c0 + tl)) : (c0 + tl);
      size_t r = (size_t)b*SEQ + phys;
      float zval = b2f(zx[r*DINPROJ + h*HEADDIM + p]);
      float sil  = zval / (1.f + expf(-zval));
      yg[((size_t)dir*ROWS + r)*DINNER + h*HEADDIM + p] = f2b(y * sil);
    }
    __syncthreads();
  }
}

// ---- per-row gated RMSNorm both dirs + combine (fp32 norm_w) -> u bf16 ----
__global__ __launch_bounds__(256) void rmscomb_kernel(const __hip_bfloat16* __restrict__ yg,
    const float* __restrict__ nw, __hip_bfloat16* __restrict__ u)
{
  __shared__ float sh[4];
  const int row = blockIdx.x;
  const __hip_bfloat16* yf = yg + (size_t)row*DINNER;
  const __hip_bfloat16* yb = yg + (size_t)(ROWS + row)*DINNER;
  float vf[6], vb[6]; float sf = 0.f, sb = 0.f;
  #pragma unroll
  for (int i = 0; i < 6; i++){
    int c = threadIdx.x + i*256;
    vf[i] = b2f(yf[c]); sf += vf[i]*vf[i];
    vb[i] = b2f(yb[c]); sb += vb[i]*vb[i];
  }
  sf = block_sum256(sf, sh);
  sb = block_sum256(sb, sh);
  float rf = rsqrtf(sf*(1.f/DINNER) + EPSF);
  float rb = rsqrtf(sb*(1.f/DINNER) + EPSF);
  #pragma unroll
  for (int i = 0; i < 6; i++){
    int c = threadIdx.x + i*256;
    u[(size_t)row*DINNER + c] = f2b((vf[i]*rf + vb[i]*rb) * nw[c]);
  }
}

// ---- ln2 on fp32 mo -> bf16 mb ----
__global__ __launch_bounds__(256) void ln2_kernel(const float* __restrict__ in,
    const float* __restrict__ w, const float* __restrict__ b,
    __hip_bfloat16* __restrict__ out)
{
  __shared__ float sh[4];
  const int row = blockIdx.x;
  const float* xr = in + (size_t)row * DMODEL;
  float v[3]; float s = 0.f;
  #pragma unroll
  for (int i = 0; i < 3; i++){ int c = threadIdx.x + i*256; v[i] = xr[c]; s += v[i]; }
  s = block_sum256(s, sh);
  float mu = s * (1.f/DMODEL);
  float s2 = 0.f;
  #pragma unroll
  for (int i = 0; i < 3; i++){ float d = v[i]-mu; s2 += d*d; }
  s2 = block_sum256(s2, sh);
  float rs = rsqrtf(s2*(1.f/DMODEL) + EPSF);
  #pragma unroll
  for (int i = 0; i < 3; i++){
    int c = threadIdx.x + i*256;
    out[(size_t)row*DMODEL + c] = f2b((v[i]-mu)*rs*w[c] + b[c]);
  }
}

// ---- exact GELU with fp32 bias: bf16 g -> bf16 gb ----
__global__ __launch_bounds__(256) void gelu_kernel(const __hip_bfloat16* __restrict__ g,
    const float* __restrict__ b1, __hip_bfloat16* __restrict__ out)
{
  size_t idx = (size_t)blockIdx.x*256 + threadIdx.x;
  int c = (int)(idx % DFF);
  float v = b2f(g[idx]) + b1[c];
  out[idx] = f2b(0.5f * v * (1.f + erff(v * 0.70710678118654752f)));
}

// ---- final: fp32 fo + fp32 bias + fp32 x -> fp32 out ----
__global__ __launch_bounds__(256) void final_kernel(const float* __restrict__ f,
    const float* __restrict__ bias, const float* __restrict__ x,
    float* __restrict__ out)
{
  size_t idx = (size_t)blockIdx.x*256 + threadIdx.x;
  int c = (int)(idx % DMODEL);
  out[idx] = f[idx] + bias[c] + x[idx];
}

extern "C" void kernel_launch(void* const* d_in, const int* in_sizes, int n_in,
                              void* d_out, int out_size, void* d_ws, size_t ws_size,
                              hipStream_t stream)
{
  float* out = (float*)d_out;

  const size_t NEED = 19906560;   // base plan (proven to fit)
  if (ws_size < NEED || n_in < 17){
    zerof_kernel<<<(out_size + 255)/256, 256, 0, stream>>>(out, out_size);
    return;
  }

  const float* x       = (const float*)d_in[0];
  const float* in_proj_w = (const float*)d_in[1];
  const float* conv_w  = (const float*)d_in[2];
  const float* conv_b  = (const float*)d_in[3];
  const float* dt_bias = (const float*)d_in[4];
  const float* A_log   = (const float*)d_in[5];
  const float* D_param = (const float*)d_in[6];
  const float* norm_w  = (const float*)d_in[7];
  const float* out_proj_w = (const float*)d_in[8];
  const float* ln1_w   = (const float*)d_in[9];
  const float* ln1_b   = (const float*)d_in[10];
  const float* ln2_w   = (const float*)d_in[11];
  const float* ln2_b   = (const float*)d_in[12];
  const float* ff_w1   = (const float*)d_in[13];
  const float* ff_b1   = (const float*)d_in[14];
  const float* ff_w2   = (const float*)d_in[15];
  const float* ff_b2   = (const float*)d_in[16];

  char* ws = (char*)d_ws;
  __hip_bfloat16* zx  = (__hip_bfloat16*)(ws + 0);         // 6,602,752
  __hip_bfloat16* xn  = (__hip_bfloat16*)(ws + 6602752);   // 1,572,864 (dead after s2)
  float*          dtb = (float*)(ws + 6602752);            //    98,304 (over xn)
  float*          dab = (float*)(ws + 6701056);            //    98,304
  __hip_bfloat16* xcv = (__hip_bfloat16*)(ws + 6799360);   // 6,815,744 -> 13,615,104
  __hip_bfloat16* yg  = (__hip_bfloat16*)(ws + 13615104);  // 6,291,456 -> 19,906,560
  __hip_bfloat16* u   = (__hip_bfloat16*)(ws + 0);         // over zx (dead after scan)
  float*          mo  = (float*)(ws + 3145728);            // over zx
  __hip_bfloat16* mb  = (__hip_bfloat16*)(ws + 0);         // over u (dead)
  __hip_bfloat16* g   = (__hip_bfloat16*)(ws + 6799360);   // over xcv (dead)
  __hip_bfloat16* gb  = (__hip_bfloat16*)(ws + 13615104);  // over yg (dead)
  float*          fo  = (float*)(ws + 0);                  // over mb (dead)

  // chunked-scan state buffer (beyond base plan): pick NC by available ws.
  // bytes per chunk = 4 (b,dir) * 24 heads * 64*64 state * 4B = 1,572,864
  const size_t CHB = 1572864;
  int NC = 1;
  if      (ws_size >= NEED + 8*CHB) NC = 8;
  else if (ws_size >= NEED + 4*CHB) NC = 4;
  else if (ws_size >= NEED + 2*CHB) NC = 2;
  float* stateBuf = (float*)(ws + NEED);
  const int CL = SEQ / NC;

  // 1) ln1(x) -> xn
  ln_kernel<<<ROWS, 256, 0, stream>>>(x, ln1_w, ln1_b, xn);
  // 2) in_proj (shared fwd/bwd) -> zx bf16  [MFMA]
  gemm_mfma<<<dim3((DINPROJ+63)/64, ROWS/64), 256, 0, stream>>>(xn, in_proj_w, zx, ROWS, DINPROJ, DMODEL);
  // 3) conv + silu + dt/dA
  convdt_kernel<<<dim3(SEQ, BSZ, 2), 256, 0, stream>>>(zx, conv_w, conv_b, dt_bias, A_log, xcv, dtb, dab);
  // 4) chunked scan
  if (NC > 1){
    scan_pass1<<<dim3(NC-1, NHEADS, 4), 256, 0, stream>>>(xcv, dtb, dab, stateBuf, CL);
    scan_fixup<<<dim3(NHEADS, 4), 256, 0, stream>>>(dab, stateBuf, NC, CL);
  }
  scan_pass2<<<dim3(NC, NHEADS, 4), 256, 0, stream>>>(xcv, zx, dtb, dab, D_param, stateBuf, yg, CL);
  // 5) per-dir RMS + combine -> u
  rmscomb_kernel<<<ROWS, 256, 0, stream>>>(yg, norm_w, u);
  // 6) out_proj -> mo fp32  [MFMA]
  gemm_mfma<<<dim3(DMODEL/64, ROWS/64), 256, 0, stream>>>(u, out_proj_w, mo, ROWS, DMODEL, DINNER);
  // 7) ln2 -> mb
  ln2_kernel<<<ROWS, 256, 0, stream>>>(mo, ln2_w, ln2_b, mb);
  // 8) ff1 -> g  [MFMA]
  gemm_mfma<<<dim3(DFF/64, ROWS/64), 256, 0, stream>>>(mb, ff_w1, g, ROWS, DFF, DMODEL);
  // 9) gelu -> gb
  gelu_kernel<<<(ROWS*DFF)/256, 256, 0, stream>>>(g, ff_b1, gb);
  // 10) ff2 -> fo fp32  [MFMA]
  gemm_mfma<<<dim3(DMODEL/64, ROWS/64), 256, 0, stream>>>(gb, ff_w2, fo, ROWS, DMODEL, DFF);
  // 11) + b2 + residual -> out fp32
  final_kernel<<<(ROWS*DMODEL)/256, 256, 0, stream>>>(fo, ff_b2, x, out);
}